// Round 12
// baseline (305.322 us; speedup 1.0000x reference)
//
#include <hip/hip_runtime.h>

#define EPS 1e-20f
typedef float f4 __attribute__((ext_vector_type(4)));

// ws layout (floats): [0,288)   sw  = softplus(spatial_weight) [c*9+k]
//                     [288,1312) cwT = softplus(channel_weight) transposed [c*32+o]
//                     [1312] 1/sum(sw), [1313] 1/sum(cw)
__global__ void prep_weights(const float* __restrict__ channel_weight, // [32*32] = [o][c]
                             const float* __restrict__ spatial_weight, // [32*9]
                             float* __restrict__ ws) {
    __shared__ float red[256];
    int tid = threadIdx.x;
    float local_sw = 0.f, local_cw = 0.f;
    for (int i = tid; i < 288; i += 256) {
        float x = spatial_weight[i];
        float v = fmaxf(x, 0.f) + log1pf(expf(-fabsf(x)));
        ws[i] = v;
        local_sw += v;
    }
    for (int i = tid; i < 1024; i += 256) {
        float x = channel_weight[i];   // i = o*32 + c
        float v = fmaxf(x, 0.f) + log1pf(expf(-fabsf(x)));
        int o = i >> 5, c = i & 31;
        ws[288 + c * 32 + o] = v;      // transposed store
        local_cw += v;
    }
    red[tid] = local_sw;
    __syncthreads();
    for (int s = 128; s > 0; s >>= 1) {
        if (tid < s) red[tid] += red[tid + s];
        __syncthreads();
    }
    if (tid == 0) ws[1312] = 1.0f / red[0];
    __syncthreads();
    red[tid] = local_cw;
    __syncthreads();
    for (int s = 128; s > 0; s >>= 1) {
        if (tid < s) red[tid] += red[tid + s];
        __syncthreads();
    }
    if (tid == 0) ws[1313] = 1.0f / red[0];
}

// Tile per block = (b, h, quarter-row) = 64 px x 32 ch. LDS = 20,480 B -> 8 blocks/CU
// (32 waves/CU = HW cap) so stage-1 (global loads) and stage-2 (LDS-only) phases of
// co-resident blocks decorrelate and the HBM pipe stays fed.
// Stage 1: wave w, iter 0..1: c = w*8 + iter*4 + cs (cs = (lane>>4)&3), pq = lane&15.
//   Each global load instruction = 4 dense 256B segments (one per channel).
// Stage 2: thread (og = tid>>4 -> o0 = og*2, pq = tid&15): 2 outputs x 4 px from LDS.
// LDS b128 ops; per-16-lane phase: writes 256B dense (2/bank, free), reads dense or broadcast.
__global__ __launch_bounds__(256, 8) void fused7(
    const float* __restrict__ d,
    const float* __restrict__ cd,
    const float* __restrict__ sp,     // [B,Cin,9,H,W]
    const float* __restrict__ wsbuf,
    const float* __restrict__ bias,   // [32]
    float* __restrict__ out)          // d_out [4,32,256,256] then cd_out
{
    __shared__ float lt[32 * 64];     // nom*inv_sum_sw,  [c][pq*4 + p]
    __shared__ float lc[32 * 64];     // cdsp = den*inv_sum_sw
    __shared__ float lcw[1024];       // [c][o]

    const int plane = 65536;

    // chunked XCD swizzle: XCD k (= orig%8) gets 512 consecutive bids (4096 % 8 == 0)
    int bid = blockIdx.x;
    bid = (bid & 7) * 512 + (bid >> 3);

    const int qt = bid & 3;           // column quarter (64 cols)
    const int h  = (bid >> 2) & 255;
    const int b  = bid >> 10;

    const int tid = threadIdx.x;

    // cooperative: channel weights -> LDS (consumed after the barrier)
    #pragma unroll
    for (int i = 0; i < 4; ++i) lcw[i * 256 + tid] = wsbuf[288 + i * 256 + tid];

    // ---------------- stage 1 ----------------
    const int w    = tid >> 6;        // wave 0..3
    const int cs   = (tid >> 4) & 3;  // channel-sub within wave
    const int pq   = tid & 15;        // quad within quarter-row
    const int col0 = qt * 64 + pq * 4;
    const float inv_sum_sw = wsbuf[1312];
    const bool rowv0 = (h >= 1), rowv2 = (h <= 254);

    #pragma unroll 1
    for (int iter = 0; iter < 2; ++iter) {
        const int c  = w * 8 + iter * 4 + cs;
        const int bc = b * 32 + c;
        const float* __restrict__ dC  = d  + (size_t)bc * plane;
        const float* __restrict__ cdC = cd + (size_t)bc * plane;
        const float* __restrict__ spC = sp + (size_t)bc * 9 * plane + h * 256;

        f4 spv[9];
        #pragma unroll
        for (int k = 0; k < 9; ++k)
            spv[k] = __builtin_nontemporal_load((const f4*)(spC + (size_t)k * plane + col0));

        float dr[3][6], cr[3][6];     // cols col0-1 .. col0+4
        #pragma unroll
        for (int i = 0; i < 3; ++i) {
            const int hh = h + i - 1;
            const int hc = min(max(hh, 0), 255);
            const float* __restrict__ drow = dC  + hc * 256;
            const float* __restrict__ crow = cdC + hc * 256;
            f4 dv = *(const f4*)(drow + col0);
            f4 cv = *(const f4*)(crow + col0);
            dr[i][1] = dv[0]; dr[i][2] = dv[1]; dr[i][3] = dv[2]; dr[i][4] = dv[3];
            cr[i][1] = cv[0]; cr[i][2] = cv[1]; cr[i][3] = cv[2]; cr[i][4] = cv[3];
            dr[i][0] = drow[max(col0 - 1, 0)];
            cr[i][0] = crow[max(col0 - 1, 0)];
            dr[i][5] = drow[min(col0 + 4, 255)];
            cr[i][5] = crow[min(col0 + 4, 255)];
        }

        float swk[9];
        #pragma unroll
        for (int k = 0; k < 9; ++k) swk[k] = wsbuf[c * 9 + k];

        float nom[4] = {0.f, 0.f, 0.f, 0.f}, den[4] = {0.f, 0.f, 0.f, 0.f};
        #pragma unroll
        for (int i = 0; i < 3; ++i) {
            const bool rv = (i == 0) ? rowv0 : ((i == 2) ? rowv2 : true);
            #pragma unroll
            for (int j = 0; j < 3; ++j) {
                const int k = i * 3 + j;
                const float s = swk[k];
                #pragma unroll
                for (int p = 0; p < 4; ++p) {
                    const int ww = col0 + p + j - 1;
                    const bool valid = rv && ((unsigned)ww < 256u);
                    const float cdp = valid ? cr[i][p + j] * spv[k][p] : 0.f;
                    nom[p] = fmaf(cdp * dr[i][p + j], s, nom[p]);
                    den[p] = fmaf(cdp, s, den[p]);
                }
            }
        }

        // t = cdsp*dsp = (den*inv)*(nom/(den+EPS)) ~= nom*inv  (rel err EPS/(den+EPS))
        f4 tv, cv4;
        #pragma unroll
        for (int p = 0; p < 4; ++p) {
            tv[p]  = nom[p] * inv_sum_sw;
            cv4[p] = den[p] * inv_sum_sw;
        }
        *(f4*)&lt[c * 64 + pq * 4] = tv;      // single ds_write_b128
        *(f4*)&lc[c * 64 + pq * 4] = cv4;
    }

    __syncthreads();

    // ---------------- stage 2 ----------------
    const int og = tid >> 4;          // 0..15 -> o = og*2, og*2+1
    const int o0 = og * 2;

    float n2[2][4], d2[2][4];
    #pragma unroll
    for (int oi = 0; oi < 2; ++oi)
        #pragma unroll
        for (int j = 0; j < 4; ++j) { n2[oi][j] = 0.f; d2[oi][j] = 0.f; }

    for (int cc = 0; cc < 32; ++cc) {
        const f4 tq = *(const f4*)&lt[cc * 64 + pq * 4];   // ds_read_b128, dense/phase
        const f4 cq = *(const f4*)&lc[cc * 64 + pq * 4];
        const float cw0 = lcw[cc * 32 + o0];               // broadcast within phase
        const float cw1 = lcw[cc * 32 + o0 + 1];
        #pragma unroll
        for (int j = 0; j < 4; ++j) {
            n2[0][j] = fmaf(tq[j], cw0, n2[0][j]);
            d2[0][j] = fmaf(cq[j], cw0, d2[0][j]);
            n2[1][j] = fmaf(tq[j], cw1, n2[1][j]);
            d2[1][j] = fmaf(cq[j], cw1, d2[1][j]);
        }
    }

    const float inv_sum_cw = wsbuf[1313];

    #pragma unroll
    for (int oi = 0; oi < 2; ++oi) {
        const float bo = bias[o0 + oi];
        f4 dv, cv;
        #pragma unroll
        for (int j = 0; j < 4; ++j) {
            dv[j] = n2[oi][j] / (d2[oi][j] + EPS) + bo;
            cv[j] = d2[oi][j] * inv_sum_cw;   // STRIDE=1
        }
        const size_t po = (size_t)(b * 32 + o0 + oi) * plane + h * 256 + col0;
        *(f4*)(out + po)           = dv;
        *(f4*)(out + 8388608 + po) = cv;
    }
}

extern "C" void kernel_launch(void* const* d_in, const int* in_sizes, int n_in,
                              void* d_out, int out_size, void* d_ws, size_t ws_size,
                              hipStream_t stream) {
    const float* d    = (const float*)d_in[0];
    const float* cd   = (const float*)d_in[1];
    // d_in[2] = s, d_in[3] = cs : unused in forward
    const float* sp   = (const float*)d_in[4];
    const float* cwt  = (const float*)d_in[5];
    const float* swt  = (const float*)d_in[6];
    const float* bias = (const float*)d_in[7];
    float* out = (float*)d_out;
    float* ws  = (float*)d_ws;

    prep_weights<<<1, 256, 0, stream>>>(cwt, swt, ws);
    fused7<<<4096, 256, 0, stream>>>(d, cd, sp, ws, bias, out);
}

// Round 13
// 105.103 us; speedup vs baseline: 2.9050x; 2.9050x over previous
//
#include <hip/hip_runtime.h>

#define EPS 1e-20f
typedef float f4 __attribute__((ext_vector_type(4)));

// ws layout (floats): [0,288)   sw  = softplus(spatial_weight) [c*9+k]
//                     [288,1312) cwT = softplus(channel_weight) transposed [c*32+o]
//                     [1312] 1/sum(sw), [1313] 1/sum(cw)
__global__ void prep_weights(const float* __restrict__ channel_weight, // [32*32] = [o][c]
                             const float* __restrict__ spatial_weight, // [32*9]
                             float* __restrict__ ws) {
    __shared__ float red[256];
    int tid = threadIdx.x;
    float local_sw = 0.f, local_cw = 0.f;
    for (int i = tid; i < 288; i += 256) {
        float x = spatial_weight[i];
        float v = fmaxf(x, 0.f) + log1pf(expf(-fabsf(x)));
        ws[i] = v;
        local_sw += v;
    }
    for (int i = tid; i < 1024; i += 256) {
        float x = channel_weight[i];   // i = o*32 + c
        float v = fmaxf(x, 0.f) + log1pf(expf(-fabsf(x)));
        int o = i >> 5, c = i & 31;
        ws[288 + c * 32 + o] = v;      // transposed store
        local_cw += v;
    }
    red[tid] = local_sw;
    __syncthreads();
    for (int s = 128; s > 0; s >>= 1) {
        if (tid < s) red[tid] += red[tid + s];
        __syncthreads();
    }
    if (tid == 0) ws[1312] = 1.0f / red[0];
    __syncthreads();
    red[tid] = local_cw;
    __syncthreads();
    for (int s = 128; s > 0; s >>= 1) {
        if (tid < s) red[tid] += red[tid + s];
        __syncthreads();
    }
    if (tid == 0) ws[1313] = 1.0f / red[0];
}

// Tile per block = (b, h, quarter-row) = 64 px x 32 ch. LDS = 20,480 B -> up to
// 8 blocks/CU at runtime (160 KiB / 20,480 = 8), so stage-1 (global loads) and
// stage-2 (LDS-only) phases of co-resident blocks decorrelate.
// NOTE: no min-waves launch_bounds — R12 showed (256,8) caps VGPR at 32 and the
// ~70-float live set spills to scratch (WRITE_SIZE 585 MB). Natural alloc ~60 VGPR.
// Stage 1: wave w, iter 0..1: c = w*8 + iter*4 + cs (cs = (lane>>4)&3), pq = lane&15.
//   Each global load instruction = 4 dense 256B segments (one per channel).
// Stage 2: thread (og = tid>>4 -> o0 = og*2, pq = tid&15): 2 outputs x 4 px from LDS.
// LDS b128 ops; per-16-lane phase: writes 256B dense (2/bank, free), reads dense or broadcast.
__global__ __launch_bounds__(256) void fused8(
    const float* __restrict__ d,
    const float* __restrict__ cd,
    const float* __restrict__ sp,     // [B,Cin,9,H,W]
    const float* __restrict__ wsbuf,
    const float* __restrict__ bias,   // [32]
    float* __restrict__ out)          // d_out [4,32,256,256] then cd_out
{
    __shared__ float lt[32 * 64];     // nom*inv_sum_sw,  [c][pq*4 + p]
    __shared__ float lc[32 * 64];     // cdsp = den*inv_sum_sw
    __shared__ float lcw[1024];       // [c][o]

    const int plane = 65536;

    // chunked XCD swizzle: XCD k (= orig%8) gets 512 consecutive bids (4096 % 8 == 0)
    int bid = blockIdx.x;
    bid = (bid & 7) * 512 + (bid >> 3);

    const int qt = bid & 3;           // column quarter (64 cols)
    const int h  = (bid >> 2) & 255;
    const int b  = bid >> 10;

    const int tid = threadIdx.x;

    // cooperative: channel weights -> LDS (consumed after the barrier)
    #pragma unroll
    for (int i = 0; i < 4; ++i) lcw[i * 256 + tid] = wsbuf[288 + i * 256 + tid];

    // ---------------- stage 1 ----------------
    const int w    = tid >> 6;        // wave 0..3
    const int cs   = (tid >> 4) & 3;  // channel-sub within wave
    const int pq   = tid & 15;        // quad within quarter-row
    const int col0 = qt * 64 + pq * 4;
    const float inv_sum_sw = wsbuf[1312];
    const bool rowv0 = (h >= 1), rowv2 = (h <= 254);

    #pragma unroll 1
    for (int iter = 0; iter < 2; ++iter) {
        const int c  = w * 8 + iter * 4 + cs;
        const int bc = b * 32 + c;
        const float* __restrict__ dC  = d  + (size_t)bc * plane;
        const float* __restrict__ cdC = cd + (size_t)bc * plane;
        const float* __restrict__ spC = sp + (size_t)bc * 9 * plane + h * 256;

        f4 spv[9];
        #pragma unroll
        for (int k = 0; k < 9; ++k)
            spv[k] = __builtin_nontemporal_load((const f4*)(spC + (size_t)k * plane + col0));

        float dr[3][6], cr[3][6];     // cols col0-1 .. col0+4
        #pragma unroll
        for (int i = 0; i < 3; ++i) {
            const int hh = h + i - 1;
            const int hc = min(max(hh, 0), 255);
            const float* __restrict__ drow = dC  + hc * 256;
            const float* __restrict__ crow = cdC + hc * 256;
            f4 dv = *(const f4*)(drow + col0);
            f4 cv = *(const f4*)(crow + col0);
            dr[i][1] = dv[0]; dr[i][2] = dv[1]; dr[i][3] = dv[2]; dr[i][4] = dv[3];
            cr[i][1] = cv[0]; cr[i][2] = cv[1]; cr[i][3] = cv[2]; cr[i][4] = cv[3];
            dr[i][0] = drow[max(col0 - 1, 0)];
            cr[i][0] = crow[max(col0 - 1, 0)];
            dr[i][5] = drow[min(col0 + 4, 255)];
            cr[i][5] = crow[min(col0 + 4, 255)];
        }

        float swk[9];
        #pragma unroll
        for (int k = 0; k < 9; ++k) swk[k] = wsbuf[c * 9 + k];

        float nom[4] = {0.f, 0.f, 0.f, 0.f}, den[4] = {0.f, 0.f, 0.f, 0.f};
        #pragma unroll
        for (int i = 0; i < 3; ++i) {
            const bool rv = (i == 0) ? rowv0 : ((i == 2) ? rowv2 : true);
            #pragma unroll
            for (int j = 0; j < 3; ++j) {
                const int k = i * 3 + j;
                const float s = swk[k];
                #pragma unroll
                for (int p = 0; p < 4; ++p) {
                    const int ww = col0 + p + j - 1;
                    const bool valid = rv && ((unsigned)ww < 256u);
                    const float cdp = valid ? cr[i][p + j] * spv[k][p] : 0.f;
                    nom[p] = fmaf(cdp * dr[i][p + j], s, nom[p]);
                    den[p] = fmaf(cdp, s, den[p]);
                }
            }
        }

        // t = cdsp*dsp = (den*inv)*(nom/(den+EPS)) ~= nom*inv  (rel err EPS/(den+EPS))
        f4 tv, cv4;
        #pragma unroll
        for (int p = 0; p < 4; ++p) {
            tv[p]  = nom[p] * inv_sum_sw;
            cv4[p] = den[p] * inv_sum_sw;
        }
        *(f4*)&lt[c * 64 + pq * 4] = tv;      // single ds_write_b128
        *(f4*)&lc[c * 64 + pq * 4] = cv4;
    }

    __syncthreads();

    // ---------------- stage 2 ----------------
    const int og = tid >> 4;          // 0..15 -> o = og*2, og*2+1
    const int o0 = og * 2;

    float n2[2][4], d2[2][4];
    #pragma unroll
    for (int oi = 0; oi < 2; ++oi)
        #pragma unroll
        for (int j = 0; j < 4; ++j) { n2[oi][j] = 0.f; d2[oi][j] = 0.f; }

    for (int cc = 0; cc < 32; ++cc) {
        const f4 tq = *(const f4*)&lt[cc * 64 + pq * 4];   // ds_read_b128, dense/phase
        const f4 cq = *(const f4*)&lc[cc * 64 + pq * 4];
        const float cw0 = lcw[cc * 32 + o0];               // broadcast within phase
        const float cw1 = lcw[cc * 32 + o0 + 1];
        #pragma unroll
        for (int j = 0; j < 4; ++j) {
            n2[0][j] = fmaf(tq[j], cw0, n2[0][j]);
            d2[0][j] = fmaf(cq[j], cw0, d2[0][j]);
            n2[1][j] = fmaf(tq[j], cw1, n2[1][j]);
            d2[1][j] = fmaf(cq[j], cw1, d2[1][j]);
        }
    }

    const float inv_sum_cw = wsbuf[1313];

    #pragma unroll
    for (int oi = 0; oi < 2; ++oi) {
        const float bo = bias[o0 + oi];
        f4 dv, cv;
        #pragma unroll
        for (int j = 0; j < 4; ++j) {
            dv[j] = n2[oi][j] / (d2[oi][j] + EPS) + bo;
            cv[j] = d2[oi][j] * inv_sum_cw;   // STRIDE=1
        }
        const size_t po = (size_t)(b * 32 + o0 + oi) * plane + h * 256 + col0;
        *(f4*)(out + po)           = dv;
        *(f4*)(out + 8388608 + po) = cv;
    }
}

extern "C" void kernel_launch(void* const* d_in, const int* in_sizes, int n_in,
                              void* d_out, int out_size, void* d_ws, size_t ws_size,
                              hipStream_t stream) {
    const float* d    = (const float*)d_in[0];
    const float* cd   = (const float*)d_in[1];
    // d_in[2] = s, d_in[3] = cs : unused in forward
    const float* sp   = (const float*)d_in[4];
    const float* cwt  = (const float*)d_in[5];
    const float* swt  = (const float*)d_in[6];
    const float* bias = (const float*)d_in[7];
    float* out = (float*)d_out;
    float* ws  = (float*)d_ws;

    prep_weights<<<1, 256, 0, stream>>>(cwt, swt, ws);
    fused8<<<4096, 256, 0, stream>>>(d, cd, sp, ws, bias, out);
}

// Round 14
// 97.746 us; speedup vs baseline: 3.1236x; 1.0753x over previous
//
#include <hip/hip_runtime.h>

#define EPS 1e-20f
typedef float f4 __attribute__((ext_vector_type(4)));

// ws layout (floats): [0,288)   sw  = softplus(spatial_weight) [c*9+k]
//                     [288,1312) cwT = softplus(channel_weight) transposed [c*32+o]
//                     [1312] 1/sum(sw), [1313] 1/sum(cw)
__global__ void prep_weights(const float* __restrict__ channel_weight, // [32*32] = [o][c]
                             const float* __restrict__ spatial_weight, // [32*9]
                             float* __restrict__ ws) {
    __shared__ float red[256];
    int tid = threadIdx.x;
    float local_sw = 0.f, local_cw = 0.f;
    for (int i = tid; i < 288; i += 256) {
        float x = spatial_weight[i];
        float v = fmaxf(x, 0.f) + log1pf(expf(-fabsf(x)));
        ws[i] = v;
        local_sw += v;
    }
    for (int i = tid; i < 1024; i += 256) {
        float x = channel_weight[i];   // i = o*32 + c
        float v = fmaxf(x, 0.f) + log1pf(expf(-fabsf(x)));
        int o = i >> 5, c = i & 31;
        ws[288 + c * 32 + o] = v;      // transposed store
        local_cw += v;
    }
    red[tid] = local_sw;
    __syncthreads();
    for (int s = 128; s > 0; s >>= 1) {
        if (tid < s) red[tid] += red[tid + s];
        __syncthreads();
    }
    if (tid == 0) ws[1312] = 1.0f / red[0];
    __syncthreads();
    red[tid] = local_cw;
    __syncthreads();
    for (int s = 128; s > 0; s >>= 1) {
        if (tid < s) red[tid] += red[tid + s];
        __syncthreads();
    }
    if (tid == 0) ws[1313] = 1.0f / red[0];
}

// Per-thread register tile for one channel-iter (15 x f4 + 12 edge scalars).
struct TileRegs {
    f4 spv[9];
    f4 dv[3], cv[3];
    float dl[3], cl[3], dh[3], ch[3];
};

__device__ __forceinline__ void tile_load(TileRegs& T,
        const float* __restrict__ d, const float* __restrict__ cd,
        const float* __restrict__ sp, int bc, int h, int col0) {
    const int plane = 65536;
    const float* __restrict__ dC  = d  + (size_t)bc * plane;
    const float* __restrict__ cdC = cd + (size_t)bc * plane;
    const float* __restrict__ spC = sp + (size_t)bc * 9 * plane + h * 256;
    #pragma unroll
    for (int k = 0; k < 9; ++k)
        T.spv[k] = __builtin_nontemporal_load((const f4*)(spC + (size_t)k * plane + col0));
    #pragma unroll
    for (int i = 0; i < 3; ++i) {
        const int hc = min(max(h + i - 1, 0), 255);
        const float* __restrict__ drow = dC  + hc * 256;
        const float* __restrict__ crow = cdC + hc * 256;
        T.dv[i] = *(const f4*)(drow + col0);
        T.cv[i] = *(const f4*)(crow + col0);
        T.dl[i] = drow[max(col0 - 1, 0)];
        T.cl[i] = crow[max(col0 - 1, 0)];
        T.dh[i] = drow[min(col0 + 4, 255)];
        T.ch[i] = crow[min(col0 + 4, 255)];
    }
}

__device__ __forceinline__ void tile_compute_store(const TileRegs& T,
        float* __restrict__ lt, float* __restrict__ lc,
        const float* __restrict__ wsbuf, int c, int col0, int pq,
        float inv_sum_sw, bool rowv0, bool rowv2) {
    float dr[3][6], cr[3][6];
    #pragma unroll
    for (int i = 0; i < 3; ++i) {
        dr[i][0] = T.dl[i]; cr[i][0] = T.cl[i];
        #pragma unroll
        for (int p = 0; p < 4; ++p) { dr[i][p + 1] = T.dv[i][p]; cr[i][p + 1] = T.cv[i][p]; }
        dr[i][5] = T.dh[i]; cr[i][5] = T.ch[i];
    }
    float swk[9];
    #pragma unroll
    for (int k = 0; k < 9; ++k) swk[k] = wsbuf[c * 9 + k];

    float nom[4] = {0.f, 0.f, 0.f, 0.f}, den[4] = {0.f, 0.f, 0.f, 0.f};
    #pragma unroll
    for (int i = 0; i < 3; ++i) {
        const bool rv = (i == 0) ? rowv0 : ((i == 2) ? rowv2 : true);
        #pragma unroll
        for (int j = 0; j < 3; ++j) {
            const int k = i * 3 + j;
            const float s = swk[k];
            #pragma unroll
            for (int p = 0; p < 4; ++p) {
                const int ww = col0 + p + j - 1;
                const bool valid = rv && ((unsigned)ww < 256u);
                const float cdp = valid ? cr[i][p + j] * T.spv[k][p] : 0.f;
                nom[p] = fmaf(cdp * dr[i][p + j], s, nom[p]);
                den[p] = fmaf(cdp, s, den[p]);
            }
        }
    }
    // t = cdsp*dsp = (den*inv)*(nom/(den+EPS)) ~= nom*inv  (rel err EPS/(den+EPS))
    f4 tv, cv4;
    #pragma unroll
    for (int p = 0; p < 4; ++p) {
        tv[p]  = nom[p] * inv_sum_sw;
        cv4[p] = den[p] * inv_sum_sw;
    }
    *(f4*)&lt[c * 128 + pq * 4] = tv;      // single ds_write_b128
    *(f4*)&lc[c * 128 + pq * 4] = cv4;
}

__device__ __forceinline__ void stage2_emit(
        const float* __restrict__ lt, const float* __restrict__ lc,
        const float* __restrict__ lcw, const float* __restrict__ wsbuf,
        const float* __restrict__ bias, float* __restrict__ out,
        int b, int h, int ct, int tid) {
    const int plane = 65536;
    const int og = tid >> 5;          // 0..7 -> o = og*4 .. og*4+3
    const int pq = tid & 31;
    const int o0 = og * 4;

    float n2[4][4], d2[4][4];
    #pragma unroll
    for (int oi = 0; oi < 4; ++oi)
        #pragma unroll
        for (int j = 0; j < 4; ++j) { n2[oi][j] = 0.f; d2[oi][j] = 0.f; }

    for (int cc = 0; cc < 32; ++cc) {
        const f4 tq = *(const f4*)&lt[cc * 128 + pq * 4];   // ds_read_b128
        const f4 cq = *(const f4*)&lc[cc * 128 + pq * 4];   // lanes l/l+32 broadcast
        const f4 cw4 = *(const f4*)&lcw[cc * 32 + o0];
        #pragma unroll
        for (int oi = 0; oi < 4; ++oi)
            #pragma unroll
            for (int j = 0; j < 4; ++j) {
                n2[oi][j] = fmaf(tq[j], cw4[oi], n2[oi][j]);
                d2[oi][j] = fmaf(cq[j], cw4[oi], d2[oi][j]);
            }
    }

    const float inv_sum_cw = wsbuf[1313];
    const f4 b4 = *(const f4*)&bias[o0];
    const int colb = ct * 128 + pq * 4;

    #pragma unroll
    for (int oi = 0; oi < 4; ++oi) {
        f4 dv, cv;
        #pragma unroll
        for (int j = 0; j < 4; ++j) {
            dv[j] = n2[oi][j] / (d2[oi][j] + EPS) + b4[oi];
            cv[j] = d2[oi][j] * inv_sum_cw;   // STRIDE=1
        }
        const size_t po = (size_t)(b * 32 + o0 + oi) * plane + h * 256 + colb;
        *(f4*)(out + po)           = dv;
        *(f4*)(out + 8388608 + po) = cv;
    }
}

// Block = full row h of image b: two 128px tiles (T0 = cols 0..127, T1 = 128..255),
// software-pipelined: T1's first channel-iter loads are issued BEFORE T0's stage-2,
// so the LDS-only stage-2 window overlaps with global loads in flight (T14).
// Grid 1024 = exactly 4 blocks/CU (one residency generation).
__global__ __launch_bounds__(256) void fused9(
    const float* __restrict__ d,
    const float* __restrict__ cd,
    const float* __restrict__ sp,     // [B,Cin,9,H,W]
    const float* __restrict__ wsbuf,
    const float* __restrict__ bias,   // [32]
    float* __restrict__ out)          // d_out [4,32,256,256] then cd_out
{
    __shared__ float lt[32 * 128];    // nom*inv_sum_sw,  [c][pq*4 + p]
    __shared__ float lc[32 * 128];    // cdsp = den*inv_sum_sw
    __shared__ float lcw[1024];       // [c][o]

    // chunked XCD swizzle: XCD k (= orig%8) gets 128 consecutive bids (1024 % 8 == 0)
    int bid = blockIdx.x;
    bid = (bid & 7) * 128 + (bid >> 3);

    const int h = bid & 255;
    const int b = bid >> 8;

    const int tid = threadIdx.x;

    // cooperative: channel weights -> LDS (consumed after the first barrier)
    #pragma unroll
    for (int i = 0; i < 4; ++i) lcw[i * 256 + tid] = wsbuf[288 + i * 256 + tid];

    const int w    = tid >> 6;        // wave 0..3
    const int half = (tid >> 5) & 1;  // channel parity within wave
    const int pq   = tid & 31;        // quad within half-row
    const int colT0 = pq * 4;
    const int colT1 = 128 + pq * 4;
    const float inv_sum_sw = wsbuf[1312];
    const bool rowv0 = (h >= 1), rowv2 = (h <= 254);

    TileRegs T, P;

    // ---- T0 stage 1 ----
    #pragma unroll 1
    for (int iter = 0; iter < 4; ++iter) {
        const int c = w * 8 + iter * 2 + half;
        tile_load(T, d, cd, sp, b * 32 + c, h, colT0);
        tile_compute_store(T, lt, lc, wsbuf, c, colT0, pq, inv_sum_sw, rowv0, rowv2);
    }
    __syncthreads();

    // ---- prefetch T1 iter0 (loads fly during T0 stage 2) ----
    {
        const int c0 = w * 8 + half;
        tile_load(P, d, cd, sp, b * 32 + c0, h, colT1);
    }

    // ---- T0 stage 2 (LDS-only FMA + output stores) ----
    stage2_emit(lt, lc, lcw, wsbuf, bias, out, b, h, 0, tid);
    __syncthreads();                   // protects LDS overwrite by T1

    // ---- T1 stage 1 (iter0 from prefetched regs) ----
    {
        const int c0 = w * 8 + half;
        tile_compute_store(P, lt, lc, wsbuf, c0, colT1, pq, inv_sum_sw, rowv0, rowv2);
    }
    #pragma unroll 1
    for (int iter = 1; iter < 4; ++iter) {
        const int c = w * 8 + iter * 2 + half;
        tile_load(T, d, cd, sp, b * 32 + c, h, colT1);
        tile_compute_store(T, lt, lc, wsbuf, c, colT1, pq, inv_sum_sw, rowv0, rowv2);
    }
    __syncthreads();

    // ---- T1 stage 2 ----
    stage2_emit(lt, lc, lcw, wsbuf, bias, out, b, h, 1, tid);
}

extern "C" void kernel_launch(void* const* d_in, const int* in_sizes, int n_in,
                              void* d_out, int out_size, void* d_ws, size_t ws_size,
                              hipStream_t stream) {
    const float* d    = (const float*)d_in[0];
    const float* cd   = (const float*)d_in[1];
    // d_in[2] = s, d_in[3] = cs : unused in forward
    const float* sp   = (const float*)d_in[4];
    const float* cwt  = (const float*)d_in[5];
    const float* swt  = (const float*)d_in[6];
    const float* bias = (const float*)d_in[7];
    float* out = (float*)d_out;
    float* ws  = (float*)d_ws;

    prep_weights<<<1, 256, 0, stream>>>(cwt, swt, ws);
    fused9<<<1024, 256, 0, stream>>>(d, cd, sp, ws, bias, out);
}